// Round 1
// baseline (125.127 us; speedup 1.0000x reference)
//
#include <hip/hip_runtime.h>

#define T_LEN 262144
#define R_LEN 4000
#define NCH 64
#define WIN 12288
#define NCHUNK 126   // p = 1..126, v in [32, 4064)
#define V_OFF 4032

typedef __attribute__((ext_vector_type(8))) short bf16x8;
typedef __attribute__((ext_vector_type(4))) float f32x4;

static __device__ __forceinline__ unsigned short f2bf(float f) {
  unsigned u = __builtin_bit_cast(unsigned, f);
  unsigned r = 0x7FFFu + ((u >> 16) & 1u);
  return (unsigned short)((u + r) >> 16);
}

// Pre-arranged B fragments: Btf[((ch*126 + (p-1))*64 + lane)*8 + e]
//   = B[32p + 8*(lane>>4) + e][lane&15],  B[v][j] = k[4032 + j - v] (0 outside [0,4000))
__global__ __launch_bounds__(256) void build_btf(const float* __restrict__ src,
                                                 unsigned short* __restrict__ btf) {
  int t = blockIdx.x * blockDim.x + threadIdx.x;
  if (t >= NCH * NCHUNK * 64) return;
  int lane = t & 63;
  int pm1 = (t >> 6) % NCHUNK;
  int ch = t / (64 * NCHUNK);
  int p = pm1 + 1;
  int j = lane & 15;
  int vbase = 32 * p + 8 * (lane >> 4);
  const float* k = src + (size_t)ch * R_LEN;
  unsigned short vals[8];
#pragma unroll
  for (int e = 0; e < 8; ++e) {
    int r = V_OFF + j - (vbase + e);
    float f = (r >= 0 && r < R_LEN) ? k[r] : 0.0f;
    vals[e] = f2bf(f);
  }
  unsigned int o0 = (unsigned int)vals[0] | ((unsigned int)vals[1] << 16);
  unsigned int o1 = (unsigned int)vals[2] | ((unsigned int)vals[3] << 16);
  unsigned int o2 = (unsigned int)vals[4] | ((unsigned int)vals[5] << 16);
  unsigned int o3 = (unsigned int)vals[6] | ((unsigned int)vals[7] << 16);
  unsigned int* dst = (unsigned int*)(btf + (size_t)t * 8);
  dst[0] = o0; dst[1] = o1; dst[2] = o2; dst[3] = o3;
}

// Each block: one channel, 8192 consecutive outputs starting at T0.
// 4 waves x 8 tiles x 256 outputs. D[i][j] = out[t0 + 16i + j].
__global__ __launch_bounds__(256) void conv_main(const float* __restrict__ x,
                                                 const unsigned short* __restrict__ btf,
                                                 float* __restrict__ out) {
  __shared__ unsigned short xs[WIN];
  const int bid = blockIdx.x;
  const int ch = bid >> 5;
  const int T0 = (bid & 31) << 13;
  const float* xch = x + (size_t)ch * T_LEN;

  // Stage xs[u] = bf16(x[T0 - 4032 + u]), zero-padded outside [0, T_LEN)
  const int base = T0 - V_OFF;
  for (int u = threadIdx.x * 4; u < WIN; u += 1024) {
    int gi = base + u;
    float4 v;
    if (gi >= 0 && gi <= T_LEN - 4) {
      v = *(const float4*)(xch + gi);
    } else {
      v.x = (gi     >= 0 && gi     < T_LEN) ? xch[gi]     : 0.f;
      v.y = (gi + 1 >= 0 && gi + 1 < T_LEN) ? xch[gi + 1] : 0.f;
      v.z = (gi + 2 >= 0 && gi + 2 < T_LEN) ? xch[gi + 2] : 0.f;
      v.w = (gi + 3 >= 0 && gi + 3 < T_LEN) ? xch[gi + 3] : 0.f;
    }
    unsigned long long pk = (unsigned long long)f2bf(v.x)
                          | ((unsigned long long)f2bf(v.y) << 16)
                          | ((unsigned long long)f2bf(v.z) << 32)
                          | ((unsigned long long)f2bf(v.w) << 48);
    *(unsigned long long*)(xs + u) = pk;
  }
  __syncthreads();

  const int lane = threadIdx.x & 63;
  const int w = threadIdx.x >> 6;
  const int i16 = lane & 15;
  const int g = lane >> 4;

  f32x4 acc[8] = {};
  const bf16x8* bp = (const bf16x8*)btf + (size_t)ch * NCHUNK * 64 + lane;
  const int abase = w * 2048 + 16 * i16 + 8 * g;

  for (int p = 1; p <= NCHUNK; ++p) {
    bf16x8 bfrag = bp[(size_t)(p - 1) * 64];
    const unsigned short* ap = xs + abase + 32 * p;
#pragma unroll
    for (int m = 0; m < 8; ++m) {
      bf16x8 afrag = *(const bf16x8*)(ap + m * 256);
      acc[m] = __builtin_amdgcn_mfma_f32_16x16x32_bf16(afrag, bfrag, acc[m], 0, 0, 0);
    }
  }

  float* och = out + (size_t)ch * T_LEN + T0 + w * 2048;
#pragma unroll
  for (int m = 0; m < 8; ++m) {
    int tb = m * 256 + i16;
#pragma unroll
    for (int r = 0; r < 4; ++r) {
      och[tb + 16 * (4 * g + r)] = acc[m][r];
    }
  }
}

extern "C" void kernel_launch(void* const* d_in, const int* in_sizes, int n_in,
                              void* d_out, int out_size, void* d_ws, size_t ws_size,
                              hipStream_t stream) {
  const float* onsets  = (const float*)d_in[0];
  const float* sources = (const float*)d_in[1];
  unsigned short* btf  = (unsigned short*)d_ws;   // 64*126*64*8*2 = 8,257,536 B
  float* out = (float*)d_out;

  int nthr = NCH * NCHUNK * 64;
  build_btf<<<(nthr + 255) / 256, 256, 0, stream>>>(sources, btf);
  conv_main<<<NCH * 32, 256, 0, stream>>>(onsets, btf, out);
}